// Round 13
// baseline (3116.942 us; speedup 1.0000x reference)
//
#include <hip/hip_runtime.h>
#include <hip/hip_bf16.h>

typedef __hip_bfloat16 bf16;
typedef unsigned short u16;
typedef unsigned long long u64;
using frag   = __attribute__((ext_vector_type(8))) short;   // 8 bf16
using f32x16 = __attribute__((ext_vector_type(16))) float;  // 32x32 accumulator

static constexpr int T_  = 128;
static constexpr int B_  = 512;
static constexpr int H_  = 512;
static constexpr int K_  = 512;
static constexpr int G4_ = 2048;
static constexpr int NWG = 256;

// dynamic LDS: frag-blocked weights 128KB + exchange/transpose region 32KB
static constexpr size_t W_BYTES = 131072;
static constexpr size_t X_BYTES = 32768;
static constexpr size_t SMEM_BYTES = W_BYTES + X_BYTES;   // 163840 = 160 KiB exactly

// coherent (agent-scope, L1/L2-bypassing) 16B load — cross-XCD layer0->layer1 only
__device__ __forceinline__ frag ld_coh(const u16* p) {
  u64 lo = __hip_atomic_load((const u64*)p,       __ATOMIC_RELAXED, __HIP_MEMORY_SCOPE_AGENT);
  u64 hi = __hip_atomic_load((const u64*)(p + 4), __ATOMIC_RELAXED, __HIP_MEMORY_SCOPE_AGENT);
  union { u64 q[2]; frag f; } u;
  u.q[0] = lo; u.q[1] = hi;
  return u.f;
}

// ---------------- setup kernels ----------------

__global__ void k_f32_to_bf16_v4(const float4* __restrict__ src,
                                 ushort4* __restrict__ dst, int n4) {
  int i = blockIdx.x * blockDim.x + threadIdx.x;
  int stride = gridDim.x * blockDim.x;
  for (; i < n4; i += stride) {
    float4 v = src[i];
    ushort4 o;
    bf16 t0 = __float2bfloat16(v.x); o.x = *reinterpret_cast<u16*>(&t0);
    bf16 t1 = __float2bfloat16(v.y); o.y = *reinterpret_cast<u16*>(&t1);
    bf16 t2 = __float2bfloat16(v.z); o.z = *reinterpret_cast<u16*>(&t2);
    bf16 t3 = __float2bfloat16(v.w); o.w = *reinterpret_cast<u16*>(&t3);
    dst[i] = o;
  }
}

__global__ void k_bias(const float* __restrict__ bih0, const float* __restrict__ bhh0,
                       const float* __restrict__ bih1, const float* __restrict__ bhh1,
                       float* __restrict__ bsum0, float* __restrict__ bsum1) {
  int i = blockIdx.x * blockDim.x + threadIdx.x;
  if (i < G4_) {
    bsum0[i] = bih0[i] + bhh0[i];
    bsum1[i] = bih1[i] + bhh1[i];
  }
}

// initial h into per-layer L2-local buffers: layer0 -> bufA0 par0, layer1 -> bufA1 par1
__global__ void k_init2(const float* __restrict__ h0,
                        u16* __restrict__ bufA0, u16* __restrict__ bufA1) {
  int i = blockIdx.x * blockDim.x + threadIdx.x;
  int n = B_ * H_;
  if (i < n) {
    bf16 a = __float2bfloat16(h0[i]);
    bf16 b = __float2bfloat16(h0[n + i]);
    bufA0[i] = *reinterpret_cast<u16*>(&a);          // parity 0
    bufA1[n + i] = *reinterpret_cast<u16*>(&b);      // parity 1
  }
}

__global__ void k_zero(int* p) {
  int i = blockIdx.x * blockDim.x + threadIdx.x;
  if (i < 256) p[i] = 0;
}

// ---------------- persistent LSTM kernel ----------------
// 256 WGs x 512 thr. Mapping as R12: lb = wg&7 -> layer = lb>>2, bg = lb&3;
// cg = wg>>3. WG owns batch rows [bg*128,+128) x h-cols [cg*16,+16).
// MFMA shape: 32x32x16 bf16 — halves LDS B-read count vs 16x16x32 (M=32 reuse).
// Waves: wave = mi*2 + nj. mi 0..3 -> A rows [mi*32,+32); nj 0..1 -> gate-pair
// N-tile (32 cols = gate nj*2 cols 0-15, gate nj*2+1 cols 16-31). 64 MFMA/wave.
// Weights frag-blocked in LDS: block fb = nj*64 + s (s<32: W_ih kstep s; s>=32:
// W_hh kstep s-32); lane l holds W[gate nj*2+((l&31)>>4), hbase+(l&15)]
// [kstep*16 + (l>>5)*8 .. +7] (16B, lane-consecutive -> conflict-free b128).
// A frag (32x32x16): row = lane&31, k = kstep*16 + (lane>>5)*8 .. +7.
// C/D: col = lane&31, row = (reg&3)+8*(reg>>2)+4*(lane>>5)  [m74/m101 verified].
// Gate exchange: all waves write acc to swizzled LDS (idx = tile*1024 + c*32 +
// ((row+c)&31)); sync; each wave reads 4 gates x 4 rows for its 16-row slice
// (rows nj*16+kq*4+j of tile mi); sync; region reused as h-transpose tile.
// h paths as R12: h-self plain L2 (+ buffer_inv sc0 per phase), layer0 dual-
// stores h0 (plain->bufA0, atomic->h0buf/L3), layer1 x via ld_coh.
// Sync: per-WG flag slot; wave 0 polls 64 domain slots in parallel.
__global__ __launch_bounds__(512, 2)
void k_main(const u16* __restrict__ latb,
            const u16* __restrict__ W0i, const u16* __restrict__ W0h,
            const u16* __restrict__ W1i, const u16* __restrict__ W1h,
            const float* __restrict__ bs0, const float* __restrict__ bs1,
            const int* __restrict__ reset,   // (T,B)
            const float* __restrict__ c0,    // (2,B,H)
            u16* __restrict__ h0buf,         // [2][B][H] coherent cross-layer h0
            u16* __restrict__ bufA0,         // [2][B][H] layer0 h-self (L2-local)
            u16* __restrict__ bufA1,         // [2][B][H] layer1 h-self (L2-local)
            float* __restrict__ hidden,      // (T,B,H)
            float* __restrict__ hn,          // (2,B,H)
            float* __restrict__ cn,          // (2,B,H)
            int* __restrict__ arr) {         // 256 flag slots, one per WG
  extern __shared__ char smem_raw[];
  u16*   wlds = (u16*)smem_raw;                 // 128KB frag-blocked weights
  float* xch  = (float*)(smem_raw + W_BYTES);   // 32KB exchange / h-transpose

  const int tid   = threadIdx.x;
  const int wg    = blockIdx.x;
  const int lb    = wg & 7;
  const int layer = lb >> 2;
  const int bg    = lb & 3;
  const int cg    = wg >> 3;
  const int hbase = cg * 16;
  const int rowbase = bg * 128;
  const int wave  = tid >> 6;                  // 0..7
  const int lane  = tid & 63;
  const int r16   = lane & 15;
  const int kq    = lane >> 4;                 // 0..3 (exchange-read/elementwise)
  const int c32   = lane & 31;                 // A-row / C-col within tile
  const int hi    = lane >> 5;                 // 0..1
  const int mi    = wave >> 1;                 // row-tile 0..3 (rows mi*32)
  const int nj    = wave & 1;                  // gate-pair 0..1
  const int wrow32  = rowbase + mi * 32;               // A-tile base row
  const int wrow0_e = rowbase + mi * 32 + nj * 16;     // elementwise 16-row base

  const u16* Wih = layer ? W1i : W0i;
  const u16* Whh = layer ? W1h : W0h;
  const float* bs = layer ? bs1 : bs0;
  u16* bufA_self = layer ? bufA1 : bufA0;

  // ---- stage weights into frag-blocked LDS (once) ----
  // chunk c = fb*64 + l ; fb = nj*64 + s ; s<32 -> W_ih kstep s, else W_hh kstep s-32
  for (int it = 0; it < 16; ++it) {
    int c = it * 512 + tid;                    // 0..8191
    int fb = c >> 6, l = c & 63;
    int njb = fb >> 6, s = fb & 63;
    int gate = njb * 2 + ((l & 31) >> 4);
    int col  = hbase + (l & 15);
    int ksrc = (s & 31) * 16 + (l >> 5) * 8;
    const u16* M = (s < 32) ? Wih : Whh;
    const u16* src = M + (size_t)(gate * H_ + col) * K_ + ksrc;
    *(float4*)(wlds + ((size_t)c) * 8) = *(const float4*)src;
  }

  // per-lane gate biases (col = hbase + r16)
  float bias[4];
  #pragma unroll
  for (int g = 0; g < 4; ++g) bias[g] = bs[g * H_ + hbase + r16];

  // c-state registers: j -> row = wrow0_e + kq*4 + j, col = hbase + r16
  float creg[4];
  #pragma unroll
  for (int j = 0; j < 4; ++j)
    creg[j] = c0[((size_t)layer * B_ + (wrow0_e + kq * 4 + j)) * H_ + hbase + r16];

  __syncthreads();

  for (int p = 0; p <= T_; ++p) {
    // L1-only invalidate (h-self lines written by sibling CUs last phase).
    if (p) { asm volatile("buffer_inv sc0" ::: "memory"); }

    const int t = layer ? (p - 1) : p;
    const bool active = (t >= 0 && t < T_);
    float hnew_r[4], cnew_r[4];

    if (active) {
      const u16* X  = layer ? (h0buf + (size_t)(p & 1) * B_ * H_)
                            : (latb + (size_t)t * B_ * K_);
      const u16* Hp = bufA_self + (size_t)(p & 1) * B_ * H_;
      u16* HnA      = bufA_self + (size_t)((p + 1) & 1) * B_ * H_;
      u16* Hn0c     = h0buf + (size_t)((p + 1) & 1) * B_ * H_;   // layer0 only

      const int* rst_t = reset + (size_t)t * B_;
      const int arow = wrow32 + c32;                 // this lane's A row
      const int ra = rst_t[arow];
      const u16* xb = X  + (size_t)arow * K_ + hi * 8;
      const u16* hb = Hp + (size_t)arow * H_ + hi * 8;

      f32x16 acc = {};
      const frag zf = {};

      // merged x+h K-loop: 64 MFMA (32x32x16), in-loop loads, frag-blocked B
      if (layer == 0) {
        #pragma unroll
        for (int s = 0; s < 32; ++s) {
          frag ax = *reinterpret_cast<const frag*>(xb + s * 16);
          frag bx = *reinterpret_cast<const frag*>(
              wlds + ((size_t)((nj * 64 + s) * 64 + lane)) * 8);
          acc = __builtin_amdgcn_mfma_f32_32x32x16_bf16(ax, bx, acc, 0, 0, 0);
          frag ah = ra ? zf : *reinterpret_cast<const frag*>(hb + s * 16);
          frag bh = *reinterpret_cast<const frag*>(
              wlds + ((size_t)((nj * 64 + 32 + s) * 64 + lane)) * 8);
          acc = __builtin_amdgcn_mfma_f32_32x32x16_bf16(ah, bh, acc, 0, 0, 0);
        }
      } else {
        #pragma unroll
        for (int s = 0; s < 32; ++s) {
          frag ax = ld_coh(xb + s * 16);
          frag bx = *reinterpret_cast<const frag*>(
              wlds + ((size_t)((nj * 64 + s) * 64 + lane)) * 8);
          acc = __builtin_amdgcn_mfma_f32_32x32x16_bf16(ax, bx, acc, 0, 0, 0);
          frag ah = ra ? zf : *reinterpret_cast<const frag*>(hb + s * 16);
          frag bh = *reinterpret_cast<const frag*>(
              wlds + ((size_t)((nj * 64 + 32 + s) * 64 + lane)) * 8);
          acc = __builtin_amdgcn_mfma_f32_32x32x16_bf16(ah, bh, acc, 0, 0, 0);
        }
      }

      // ---- gate exchange: write acc to swizzled LDS tile (mi,nj) ----
      // tile base = (mi*2+nj)*1024 f32; within: idx = c*32 + ((row + c) & 31)
      {
        float* tb = xch + (size_t)(mi * 2 + nj) * 1024 + (size_t)c32 * 32;
        #pragma unroll
        for (int r = 0; r < 16; ++r) {
          int row = (r & 3) + 8 * (r >> 2) + 4 * hi;
          tb[(row + c32) & 31] = acc[r];
        }
      }
      __syncthreads();

      // ---- read 4 gates x 4 rows for this wave's 16-row slice ----
      float gval[4][4];
      #pragma unroll
      for (int g = 0; g < 4; ++g) {
        const float* tg = xch + (size_t)(mi * 2 + (g >> 1)) * 1024;
        const int cc = (g & 1) * 16 + r16;
        #pragma unroll
        for (int j = 0; j < 4; ++j) {
          int row = nj * 16 + kq * 4 + j;
          gval[g][j] = tg[cc * 32 + ((row + cc) & 31)];
        }
      }
      __syncthreads();   // exchange reads done; region reusable as h-transpose

      // ---- cell elementwise: 16 rows (wrow0_e + kq*4 + j), col r16 ----
      float* hstg = xch + (size_t)wave * 320;     // [16][20] f32, per wave
      #pragma unroll
      for (int j = 0; j < 4; ++j) {
        const int row = wrow0_e + kq * 4 + j;
        const int rstj = rst_t[row];
        float gi = gval[0][j] + bias[0];
        float gf = gval[1][j] + bias[1];
        float gg = gval[2][j] + bias[2];
        float go = gval[3][j] + bias[3];
        float iv = 1.f / (1.f + __expf(-gi));
        float fv = 1.f / (1.f + __expf(-gf));
        float gv = 1.f - 2.f / (__expf(2.f * gg) + 1.f);   // tanh
        float ov = 1.f / (1.f + __expf(-go));
        float ce = rstj ? 0.f : creg[j];
        float cnew = fv * ce + iv * gv;
        float hnew = ov * (1.f - 2.f / (__expf(2.f * cnew) + 1.f));
        creg[j] = cnew;
        cnew_r[j] = cnew;
        hnew_r[j] = hnew;
        hstg[(kq * 4 + j) * 20 + r16] = hnew;   // wave-local (in-wave DS order)
      }

      // pack + h stores: lane -> (row = lane>>2, 4 cols at (lane&3)*4)
      {
        const int prow = lane >> 2;
        const int pc4  = lane & 3;
        float4 v = *reinterpret_cast<const float4*>(hstg + prow * 20 + pc4 * 4);
        bf16 b0 = __float2bfloat16(v.x), b1 = __float2bfloat16(v.y);
        bf16 b2 = __float2bfloat16(v.z), b3 = __float2bfloat16(v.w);
        u64 pk = (u64)*reinterpret_cast<u16*>(&b0)
               | ((u64)*reinterpret_cast<u16*>(&b1) << 16)
               | ((u64)*reinterpret_cast<u16*>(&b2) << 32)
               | ((u64)*reinterpret_cast<u16*>(&b3) << 48);
        const size_t hoff = (size_t)(wrow0_e + prow) * H_ + hbase + pc4 * 4;
        *(u64*)(HnA + hoff) = pk;                       // plain -> local L2
        if (layer == 0) {
          __hip_atomic_store((u64*)(Hn0c + hoff), pk,
                             __ATOMIC_RELAXED, __HIP_MEMORY_SCOPE_AGENT);  // -> L3
        }
      }
    }

    // barrier arrival: own-slot flag store (no RMW), after h stores acked
    if (p < T_) {
      asm volatile("s_waitcnt vmcnt(0)" ::: "memory");
      __syncthreads();
      if (tid == 0)
        __hip_atomic_store(arr + wg, p + 1, __ATOMIC_RELAXED, __HIP_MEMORY_SCOPE_AGENT);
    }

    // deferred output stores (overlap with poll)
    if (active) {
      float* hidden_t = hidden + (size_t)t * B_ * H_;
      #pragma unroll
      for (int j = 0; j < 4; ++j) {
        const size_t off = (size_t)(wrow0_e + kq * 4 + j) * H_ + hbase + r16;
        if (layer) hidden_t[off] = hnew_r[j];
        if (t == T_ - 1) {
          hn[(size_t)layer * B_ * H_ + off] = hnew_r[j];
          cn[(size_t)layer * B_ * H_ + off] = cnew_r[j];
        }
      }
    }

    // barrier wait: wave 0's 64 lanes poll the 64 pair-domain slots in parallel
    if (p < T_) {
      if (wave == 0) {
        const int slot = (lane >> 1) * 8 + (lane & 1) * 4 + bg;  // all 64 domain WGs
        while (__hip_atomic_load(arr + slot, __ATOMIC_RELAXED,
                                 __HIP_MEMORY_SCOPE_AGENT) < p + 1)
          __builtin_amdgcn_s_sleep(2);
      }
      __syncthreads();
    }
  }
}

// ---------------- host ----------------

extern "C" void kernel_launch(void* const* d_in, const int* in_sizes, int n_in,
                              void* d_out, int out_size, void* d_ws, size_t ws_size,
                              hipStream_t stream) {
  (void)in_sizes; (void)n_in; (void)out_size; (void)ws_size;

  const float* latent = (const float*)d_in[0];
  const float* h0in   = (const float*)d_in[1];
  const float* c0in   = (const float*)d_in[2];
  const int*   reset  = (const int*)d_in[3];
  const float* W_ih0  = (const float*)d_in[4];
  const float* W_hh0  = (const float*)d_in[5];
  const float* b_ih0  = (const float*)d_in[6];
  const float* b_hh0  = (const float*)d_in[7];
  const float* W_ih1  = (const float*)d_in[8];
  const float* W_hh1  = (const float*)d_in[9];
  const float* b_ih1  = (const float*)d_in[10];
  const float* b_hh1  = (const float*)d_in[11];

  float* out    = (float*)d_out;
  float* hidden = out;                               // (T,B,H)
  float* hn     = out + (size_t)T_ * B_ * H_;        // (2,B,H)
  float* cn     = hn + (size_t)2 * B_ * H_;          // (2,B,H)

  // workspace layout
  char* ws = (char*)d_ws;
  u16* latb  = (u16*)ws;                             // T*B*K bf16 (64 MiB)
  u16* wih0b = latb + (size_t)T_ * B_ * K_;
  u16* whh0b = wih0b + (size_t)G4_ * K_;
  u16* wih1b = whh0b + (size_t)G4_ * K_;
  u16* whh1b = wih1b + (size_t)G4_ * K_;
  float* bsum0 = (float*)(whh1b + (size_t)G4_ * K_);
  float* bsum1 = bsum0 + G4_;
  u16* h0buf = (u16*)(bsum1 + G4_);                  // [2][B][H] coherent
  u16* bufA0 = h0buf + (size_t)2 * B_ * H_;          // [2][B][H] L2-local
  u16* bufA1 = bufA0 + (size_t)2 * B_ * H_;          // [2][B][H] L2-local
  int* arr   = (int*)(bufA1 + (size_t)2 * B_ * H_);  // 256 flag slots

  // conversions / init (stream-ordered)
  int n_lat4 = T_ * B_ * K_ / 4;
  k_f32_to_bf16_v4<<<2048, 256, 0, stream>>>((const float4*)latent, (ushort4*)latb, n_lat4);
  int n_w4 = G4_ * K_ / 4;
  k_f32_to_bf16_v4<<<256, 256, 0, stream>>>((const float4*)W_ih0, (ushort4*)wih0b, n_w4);
  k_f32_to_bf16_v4<<<256, 256, 0, stream>>>((const float4*)W_hh0, (ushort4*)whh0b, n_w4);
  k_f32_to_bf16_v4<<<256, 256, 0, stream>>>((const float4*)W_ih1, (ushort4*)wih1b, n_w4);
  k_f32_to_bf16_v4<<<256, 256, 0, stream>>>((const float4*)W_hh1, (ushort4*)whh1b, n_w4);
  k_bias<<<(G4_ + 255) / 256, 256, 0, stream>>>(b_ih0, b_hh0, b_ih1, b_hh1, bsum0, bsum1);
  k_init2<<<(B_ * H_ + 255) / 256, 256, 0, stream>>>(h0in, bufA0, bufA1);
  k_zero<<<1, 256, 0, stream>>>(arr);

  // persistent cooperative kernel
  hipFuncSetAttribute((const void*)k_main, hipFuncAttributeMaxDynamicSharedMemorySize,
                      (int)SMEM_BYTES);
  void* args[] = { (void*)&latb, (void*)&wih0b, (void*)&whh0b, (void*)&wih1b, (void*)&whh1b,
                   (void*)&bsum0, (void*)&bsum1, (void*)&reset, (void*)&c0in,
                   (void*)&h0buf, (void*)&bufA0, (void*)&bufA1,
                   (void*)&hidden, (void*)&hn, (void*)&cn, (void*)&arr };
  hipLaunchCooperativeKernel((void*)k_main, dim3(NWG), dim3(512), args,
                             (unsigned int)SMEM_BYTES, stream);
}

// Round 14
// 1893.620 us; speedup vs baseline: 1.6460x; 1.6460x over previous
//
#include <hip/hip_runtime.h>
#include <hip/hip_bf16.h>

typedef __hip_bfloat16 bf16;
typedef unsigned short u16;
typedef unsigned long long u64;
using frag   = __attribute__((ext_vector_type(8))) short;   // 8 bf16
using f32x4v = __attribute__((ext_vector_type(4))) float;
using f32x16 = __attribute__((ext_vector_type(16))) float;  // 32x32 accumulator

static constexpr int T_  = 128;
static constexpr int B_  = 512;
static constexpr int H_  = 512;
static constexpr int K_  = 512;
static constexpr int G4_ = 2048;
static constexpr int NWG = 256;

// dynamic LDS: frag-blocked weights 128KB + exchange tiles 32KB = 160 KiB exactly
static constexpr size_t W_BYTES = 131072;
static constexpr size_t X_BYTES = 32768;
static constexpr size_t SMEM_BYTES = W_BYTES + X_BYTES;   // 163840

// coherent (agent-scope, L1/L2-bypassing) 16B load — cross-XCD layer0->layer1 only
__device__ __forceinline__ frag ld_coh(const u16* p) {
  u64 lo = __hip_atomic_load((const u64*)p,       __ATOMIC_RELAXED, __HIP_MEMORY_SCOPE_AGENT);
  u64 hi = __hip_atomic_load((const u64*)(p + 4), __ATOMIC_RELAXED, __HIP_MEMORY_SCOPE_AGENT);
  union { u64 q[2]; frag f; } u;
  u.q[0] = lo; u.q[1] = hi;
  return u.f;
}

// ---------------- setup kernels ----------------

__global__ void k_f32_to_bf16_v4(const float4* __restrict__ src,
                                 ushort4* __restrict__ dst, int n4) {
  int i = blockIdx.x * blockDim.x + threadIdx.x;
  int stride = gridDim.x * blockDim.x;
  for (; i < n4; i += stride) {
    float4 v = src[i];
    ushort4 o;
    bf16 t0 = __float2bfloat16(v.x); o.x = *reinterpret_cast<u16*>(&t0);
    bf16 t1 = __float2bfloat16(v.y); o.y = *reinterpret_cast<u16*>(&t1);
    bf16 t2 = __float2bfloat16(v.z); o.z = *reinterpret_cast<u16*>(&t2);
    bf16 t3 = __float2bfloat16(v.w); o.w = *reinterpret_cast<u16*>(&t3);
    dst[i] = o;
  }
}

__global__ void k_bias(const float* __restrict__ bih0, const float* __restrict__ bhh0,
                       const float* __restrict__ bih1, const float* __restrict__ bhh1,
                       float* __restrict__ bsum0, float* __restrict__ bsum1) {
  int i = blockIdx.x * blockDim.x + threadIdx.x;
  if (i < G4_) {
    bsum0[i] = bih0[i] + bhh0[i];
    bsum1[i] = bih1[i] + bhh1[i];
  }
}

// initial h into per-layer L2-local buffers: layer0 -> bufA0 par0, layer1 -> bufA1 par1
__global__ void k_init2(const float* __restrict__ h0,
                        u16* __restrict__ bufA0, u16* __restrict__ bufA1) {
  int i = blockIdx.x * blockDim.x + threadIdx.x;
  int n = B_ * H_;
  if (i < n) {
    bf16 a = __float2bfloat16(h0[i]);
    bf16 b = __float2bfloat16(h0[n + i]);
    bufA0[i] = *reinterpret_cast<u16*>(&a);          // parity 0
    bufA1[n + i] = *reinterpret_cast<u16*>(&b);      // parity 1
  }
}

__global__ void k_zero(int* p) {
  int i = blockIdx.x * blockDim.x + threadIdx.x;
  if (i < 256) p[i] = 0;
}

// ---------------- persistent LSTM kernel ----------------
// 256 WGs x 512 thr. Mapping as R12: lb = wg&7 -> layer = lb>>2, bg = lb&3;
// cg = wg>>3. WG owns batch rows [bg*128,+128) x h-cols [cg*16,+16).
// MFMA 32x32x16. Waves: wave = mi*2 + ks. mi 0..3 -> rows [mi*32,+32);
// ks 0 = x-part (K 0..511 @ W_ih), ks 1 = h-part (@ W_hh, reset-masked).
// Per wave: 2 output tiles (gate-pair gp 0/1, 32 gate-cols each) x 32 ksteps
// = 64 MFMA, 64 B-ds_reads, 32 A-loads. No A duplication across waves;
// B-read count halved vs the 16x16 structure (M=32 reuse).
// Weights frag-blocked in LDS: block fb = gp*64 + ks*32 + s; lane l holds
// W[gate gp*2+((l&31)>>4), hbase+(l&15)][s*16 + (l>>5)*8 .. +7].
// A frag: row = lane&31 (+mi*32), k = s*16 + (lane>>5)*8 .. +7  [R13-validated]
// C/D: col = lane&31, row = (reg&3)+8*(reg>>2)+4*(lane>>5)      [R13-validated]
// K-half reduction + gate redistribution via 8 LDS tiles [col][row] f32 with
// XOR chunk swizzle dw = col*32 + (row&3) + (((row>>2)^(col&7))<<2):
//   ks1 writes partials -> sync -> ks0 adds + writes finals -> sync ->
//   both read 4-gate slices for their 16 elementwise rows -> sync.
// h paths as R12: h-self plain L2 (+ buffer_inv sc0 per phase), layer0 dual-
// stores h0 (plain->bufA0, atomic->h0buf/L3), layer1 x via ld_coh.
// Sync: per-WG flag slot; wave 0 polls 64 domain slots in parallel.
__global__ __launch_bounds__(512, 2)
void k_main(const u16* __restrict__ latb,
            const u16* __restrict__ W0i, const u16* __restrict__ W0h,
            const u16* __restrict__ W1i, const u16* __restrict__ W1h,
            const float* __restrict__ bs0, const float* __restrict__ bs1,
            const int* __restrict__ reset,   // (T,B)
            const float* __restrict__ c0,    // (2,B,H)
            u16* __restrict__ h0buf,         // [2][B][H] coherent cross-layer h0
            u16* __restrict__ bufA0,         // [2][B][H] layer0 h-self (L2-local)
            u16* __restrict__ bufA1,         // [2][B][H] layer1 h-self (L2-local)
            float* __restrict__ hidden,      // (T,B,H)
            float* __restrict__ hn,          // (2,B,H)
            float* __restrict__ cn,          // (2,B,H)
            int* __restrict__ arr) {         // 256 flag slots, one per WG
  extern __shared__ char smem_raw[];
  u16*   wlds = (u16*)smem_raw;                 // 128KB frag-blocked weights
  float* xch  = (float*)(smem_raw + W_BYTES);   // 32KB: 8 tiles x 1024 f32

  const int tid   = threadIdx.x;
  const int wg    = blockIdx.x;
  const int lb    = wg & 7;
  const int layer = lb >> 2;
  const int bg    = lb & 3;
  const int cg    = wg >> 3;
  const int hbase = cg * 16;
  const int rowbase = bg * 128;
  const int wave  = tid >> 6;                  // 0..7
  const int lane  = tid & 63;
  const int r16   = lane & 15;
  const int kq    = lane >> 4;                 // 0..3
  const int c32   = lane & 31;
  const int hi    = lane >> 5;                 // 0..1
  const int mi    = wave >> 1;                 // row-tile 0..3
  const int ks    = wave & 1;                  // K-half: 0 = x, 1 = h
  const int wrow32  = rowbase + mi * 32;
  const int wrow0_e = wrow32 + ks * 16;        // elementwise 16-row base

  const u16* Wih = layer ? W1i : W0i;
  const u16* Whh = layer ? W1h : W0h;
  const float* bs = layer ? bs1 : bs0;
  u16* bufA_self = layer ? bufA1 : bufA0;

  // ---- stage weights into frag-blocked LDS (once) ----
  // chunk c = fb*64 + l ; fb = gp*64 + ks_*32 + s ; ks_=0 -> W_ih, ks_=1 -> W_hh
  for (int it = 0; it < 16; ++it) {
    int c = it * 512 + tid;                    // 0..8191
    int fb = c >> 6, l = c & 63;
    int gp = fb >> 6, rem = fb & 63;
    int ksb = rem >> 5, s = rem & 31;
    int gate = gp * 2 + ((l & 31) >> 4);
    int col  = hbase + (l & 15);
    int ksrc = s * 16 + (l >> 5) * 8;
    const u16* M = ksb ? Whh : Wih;
    const u16* src = M + (size_t)(gate * H_ + col) * K_ + ksrc;
    *(float4*)(wlds + ((size_t)c) * 8) = *(const float4*)src;
  }

  // per-lane gate biases (col = hbase + r16)
  float bias[4];
  #pragma unroll
  for (int g = 0; g < 4; ++g) bias[g] = bs[g * H_ + hbase + r16];

  // c-state registers: j -> row = wrow0_e + kq*4 + j, col = hbase + r16
  float creg[4];
  #pragma unroll
  for (int j = 0; j < 4; ++j)
    creg[j] = c0[((size_t)layer * B_ + (wrow0_e + kq * 4 + j)) * H_ + hbase + r16];

  __syncthreads();

  // per-wave B base in LDS: gp0 block fb = ks*32+s ; gp1 at +64 blocks
  const u16* wb0 = wlds + (size_t)(ks * 32) * 512 + (size_t)lane * 8;

  // exchange tile bases for this wave's row-tile
  float* tb0 = xch + (size_t)(mi * 2 + 0) * 1024;
  float* tb1 = xch + (size_t)(mi * 2 + 1) * 1024;
  const int cx = c32 & 7;

  for (int p = 0; p <= T_; ++p) {
    if (p) { asm volatile("buffer_inv sc0" ::: "memory"); }   // L1-only inv

    const int t = layer ? (p - 1) : p;
    const bool active = (t >= 0 && t < T_);
    float hnew_r[4], cnew_r[4];

    if (active) {
      const u16* Hp = bufA_self + (size_t)(p & 1) * B_ * H_;
      u16* HnA      = bufA_self + (size_t)((p + 1) & 1) * B_ * H_;
      u16* Hn0c     = h0buf + (size_t)((p + 1) & 1) * B_ * H_;   // layer0 only
      const int* rst_t = reset + (size_t)t * B_;

      f32x16 acc0 = {}, acc1 = {};
      const frag zf = {};
      const int arow = wrow32 + c32;

      if (ks == 0) {
        const u16* X = layer ? (h0buf + (size_t)(p & 1) * B_ * H_)
                             : (latb + (size_t)t * B_ * K_);
        const u16* ap = X + (size_t)arow * K_ + hi * 8;
        if (layer == 0) {
          #pragma unroll
          for (int s = 0; s < 32; ++s) {
            frag a  = *reinterpret_cast<const frag*>(ap + s * 16);
            frag b0 = *reinterpret_cast<const frag*>(wb0 + (size_t)s * 512);
            frag b1 = *reinterpret_cast<const frag*>(wb0 + 32768 + (size_t)s * 512);
            acc0 = __builtin_amdgcn_mfma_f32_32x32x16_bf16(a, b0, acc0, 0, 0, 0);
            acc1 = __builtin_amdgcn_mfma_f32_32x32x16_bf16(a, b1, acc1, 0, 0, 0);
          }
        } else {
          #pragma unroll
          for (int s = 0; s < 32; ++s) {
            frag a  = ld_coh(ap + s * 16);
            frag b0 = *reinterpret_cast<const frag*>(wb0 + (size_t)s * 512);
            frag b1 = *reinterpret_cast<const frag*>(wb0 + 32768 + (size_t)s * 512);
            acc0 = __builtin_amdgcn_mfma_f32_32x32x16_bf16(a, b0, acc0, 0, 0, 0);
            acc1 = __builtin_amdgcn_mfma_f32_32x32x16_bf16(a, b1, acc1, 0, 0, 0);
          }
        }
      } else {
        const int ra = rst_t[arow];
        const u16* ap = Hp + (size_t)arow * H_ + hi * 8;
        #pragma unroll
        for (int s = 0; s < 32; ++s) {
          frag a  = ra ? zf : *reinterpret_cast<const frag*>(ap + s * 16);
          frag b0 = *reinterpret_cast<const frag*>(wb0 + (size_t)s * 512);
          frag b1 = *reinterpret_cast<const frag*>(wb0 + 32768 + (size_t)s * 512);
          acc0 = __builtin_amdgcn_mfma_f32_32x32x16_bf16(a, b0, acc0, 0, 0, 0);
          acc1 = __builtin_amdgcn_mfma_f32_32x32x16_bf16(a, b1, acc1, 0, 0, 0);
        }
      }

      // ---- step 1: ks1 waves write partial tiles (swizzled [col][row]) ----
      if (ks == 1) {
        #pragma unroll
        for (int q = 0; q < 4; ++q) {
          const int dw = c32 * 32 + (((2 * q + hi) ^ cx) << 2);
          f32x4v v0 = { acc0[q*4+0], acc0[q*4+1], acc0[q*4+2], acc0[q*4+3] };
          f32x4v v1 = { acc1[q*4+0], acc1[q*4+1], acc1[q*4+2], acc1[q*4+3] };
          *(f32x4v*)(tb0 + dw) = v0;
          *(f32x4v*)(tb1 + dw) = v1;
        }
      }
      __syncthreads();

      // ---- step 2: ks0 waves add partials, write finals to same slots ----
      if (ks == 0) {
        #pragma unroll
        for (int q = 0; q < 4; ++q) {
          const int dw = c32 * 32 + (((2 * q + hi) ^ cx) << 2);
          f32x4v p0 = *(const f32x4v*)(tb0 + dw);
          f32x4v p1 = *(const f32x4v*)(tb1 + dw);
          acc0[q*4+0] += p0[0]; acc0[q*4+1] += p0[1];
          acc0[q*4+2] += p0[2]; acc0[q*4+3] += p0[3];
          acc1[q*4+0] += p1[0]; acc1[q*4+1] += p1[1];
          acc1[q*4+2] += p1[2]; acc1[q*4+3] += p1[3];
          f32x4v v0 = { acc0[q*4+0], acc0[q*4+1], acc0[q*4+2], acc0[q*4+3] };
          f32x4v v1 = { acc1[q*4+0], acc1[q*4+1], acc1[q*4+2], acc1[q*4+3] };
          *(f32x4v*)(tb0 + dw) = v0;
          *(f32x4v*)(tb1 + dw) = v1;
        }
      }
      __syncthreads();

      // ---- step 3: read 4-gate slices for this wave's 16 rows ----
      f32x4v gv0, gv1, gv2, gv3;   // gate 0..3, rows kq*4..+3 at col hbase+r16
      {
        const int rq = ks * 4 + kq;             // row>>2 within tile (rows +ks*16)
        const int col0 = r16, col1 = 16 + r16;
        const int dw0 = col0 * 32 + ((rq ^ (col0 & 7)) << 2);
        const int dw1 = col1 * 32 + ((rq ^ (col1 & 7)) << 2);
        gv0 = *(const f32x4v*)(tb0 + dw0);      // gate 0 (gp0, lo half)
        gv1 = *(const f32x4v*)(tb0 + dw1);      // gate 1 (gp0, hi half)
        gv2 = *(const f32x4v*)(tb1 + dw0);      // gate 2 (gp1, lo half)
        gv3 = *(const f32x4v*)(tb1 + dw1);      // gate 3 (gp1, hi half)
      }
      __syncthreads();   // all tile reads done; region reusable as hstage

      // ---- elementwise: 16 rows (wrow0_e + kq*4 + j), col hbase + r16 ----
      float* hstg = xch + (size_t)wave * 320;   // [16][20] f32 per wave
      #pragma unroll
      for (int j = 0; j < 4; ++j) {
        const int row = wrow0_e + kq * 4 + j;
        const int rstj = rst_t[row];
        float gi = gv0[j] + bias[0];
        float gf = gv1[j] + bias[1];
        float gg = gv2[j] + bias[2];
        float go = gv3[j] + bias[3];
        float iv = 1.f / (1.f + __expf(-gi));
        float fv = 1.f / (1.f + __expf(-gf));
        float gvl = 1.f - 2.f / (__expf(2.f * gg) + 1.f);   // tanh
        float ov = 1.f / (1.f + __expf(-go));
        float ce = rstj ? 0.f : creg[j];
        float cnew = fv * ce + iv * gvl;
        float hnew = ov * (1.f - 2.f / (__expf(2.f * cnew) + 1.f));
        creg[j] = cnew;
        cnew_r[j] = cnew;
        hnew_r[j] = hnew;
        hstg[(kq * 4 + j) * 20 + r16] = hnew;   // wave-local (in-wave DS order)
      }

      // pack + h stores: lane -> (row = lane>>2, 4 cols at (lane&3)*4)
      {
        const int prow = lane >> 2;
        const int pc4  = lane & 3;
        f32x4v v = *(const f32x4v*)(hstg + prow * 20 + pc4 * 4);
        bf16 b0 = __float2bfloat16(v[0]), b1 = __float2bfloat16(v[1]);
        bf16 b2 = __float2bfloat16(v[2]), b3 = __float2bfloat16(v[3]);
        u64 pk = (u64)*reinterpret_cast<u16*>(&b0)
               | ((u64)*reinterpret_cast<u16*>(&b1) << 16)
               | ((u64)*reinterpret_cast<u16*>(&b2) << 32)
               | ((u64)*reinterpret_cast<u16*>(&b3) << 48);
        const size_t hoff = (size_t)(wrow0_e + prow) * H_ + hbase + pc4 * 4;
        *(u64*)(HnA + hoff) = pk;                       // plain -> local L2
        if (layer == 0) {
          __hip_atomic_store((u64*)(Hn0c + hoff), pk,
                             __ATOMIC_RELAXED, __HIP_MEMORY_SCOPE_AGENT);  // -> L3
        }
      }
    }

    // barrier arrival: own-slot flag store (no RMW), after h stores acked
    if (p < T_) {
      asm volatile("s_waitcnt vmcnt(0)" ::: "memory");
      __syncthreads();
      if (tid == 0)
        __hip_atomic_store(arr + wg, p + 1, __ATOMIC_RELAXED, __HIP_MEMORY_SCOPE_AGENT);
    }

    // deferred output stores (overlap with poll)
    if (active) {
      float* hidden_t = hidden + (size_t)t * B_ * H_;
      #pragma unroll
      for (int j = 0; j < 4; ++j) {
        const size_t off = (size_t)(wrow0_e + kq * 4 + j) * H_ + hbase + r16;
        if (layer) hidden_t[off] = hnew_r[j];
        if (t == T_ - 1) {
          hn[(size_t)layer * B_ * H_ + off] = hnew_r[j];
          cn[(size_t)layer * B_ * H_ + off] = cnew_r[j];
        }
      }
    }

    // barrier wait: wave 0's 64 lanes poll the 64 pair-domain slots in parallel
    if (p < T_) {
      if (wave == 0) {
        const int slot = (lane >> 1) * 8 + (lane & 1) * 4 + bg;  // all 64 domain WGs
        while (__hip_atomic_load(arr + slot, __ATOMIC_RELAXED,
                                 __HIP_MEMORY_SCOPE_AGENT) < p + 1)
          __builtin_amdgcn_s_sleep(2);
      }
      __syncthreads();
    }
  }
}

// ---------------- host ----------------

extern "C" void kernel_launch(void* const* d_in, const int* in_sizes, int n_in,
                              void* d_out, int out_size, void* d_ws, size_t ws_size,
                              hipStream_t stream) {
  (void)in_sizes; (void)n_in; (void)out_size; (void)ws_size;

  const float* latent = (const float*)d_in[0];
  const float* h0in   = (const float*)d_in[1];
  const float* c0in   = (const float*)d_in[2];
  const int*   reset  = (const int*)d_in[3];
  const float* W_ih0  = (const float*)d_in[4];
  const float* W_hh0  = (const float*)d_in[5];
  const float* b_ih0  = (const float*)d_in[6];
  const float* b_hh0  = (const float*)d_in[7];
  const float* W_ih1  = (const float*)d_in[8];
  const float* W_hh1  = (const float*)d_in[9];
  const float* b_ih1  = (const float*)d_in[10];
  const float* b_hh1  = (const float*)d_in[11];

  float* out    = (float*)d_out;
  float* hidden = out;                               // (T,B,H)
  float* hn     = out + (size_t)T_ * B_ * H_;        // (2,B,H)
  float* cn     = hn + (size_t)2 * B_ * H_;          // (2,B,H)

  // workspace layout
  char* ws = (char*)d_ws;
  u16* latb  = (u16*)ws;                             // T*B*K bf16 (64 MiB)
  u16* wih0b = latb + (size_t)T_ * B_ * K_;
  u16* whh0b = wih0b + (size_t)G4_ * K_;
  u16* wih1b = whh0b + (size_t)G4_ * K_;
  u16* whh1b = wih1b + (size_t)G4_ * K_;
  float* bsum0 = (float*)(whh1b + (size_t)G4_ * K_);
  float* bsum1 = bsum0 + G4_;
  u16* h0buf = (u16*)(bsum1 + G4_);                  // [2][B][H] coherent
  u16* bufA0 = h0buf + (size_t)2 * B_ * H_;          // [2][B][H] L2-local
  u16* bufA1 = bufA0 + (size_t)2 * B_ * H_;          // [2][B][H] L2-local
  int* arr   = (int*)(bufA1 + (size_t)2 * B_ * H_);  // 256 flag slots

  // conversions / init (stream-ordered)
  int n_lat4 = T_ * B_ * K_ / 4;
  k_f32_to_bf16_v4<<<2048, 256, 0, stream>>>((const float4*)latent, (ushort4*)latb, n_lat4);
  int n_w4 = G4_ * K_ / 4;
  k_f32_to_bf16_v4<<<256, 256, 0, stream>>>((const float4*)W_ih0, (ushort4*)wih0b, n_w4);
  k_f32_to_bf16_v4<<<256, 256, 0, stream>>>((const float4*)W_hh0, (ushort4*)whh0b, n_w4);
  k_f32_to_bf16_v4<<<256, 256, 0, stream>>>((const float4*)W_ih1, (ushort4*)wih1b, n_w4);
  k_f32_to_bf16_v4<<<256, 256, 0, stream>>>((const float4*)W_hh1, (ushort4*)whh1b, n_w4);
  k_bias<<<(G4_ + 255) / 256, 256, 0, stream>>>(b_ih0, b_hh0, b_ih1, b_hh1, bsum0, bsum1);
  k_init2<<<(B_ * H_ + 255) / 256, 256, 0, stream>>>(h0in, bufA0, bufA1);
  k_zero<<<1, 256, 0, stream>>>(arr);

  // persistent cooperative kernel
  hipFuncSetAttribute((const void*)k_main, hipFuncAttributeMaxDynamicSharedMemorySize,
                      (int)SMEM_BYTES);
  void* args[] = { (void*)&latb, (void*)&wih0b, (void*)&whh0b, (void*)&wih1b, (void*)&whh1b,
                   (void*)&bsum0, (void*)&bsum1, (void*)&reset, (void*)&c0in,
                   (void*)&h0buf, (void*)&bufA0, (void*)&bufA1,
                   (void*)&hidden, (void*)&hn, (void*)&cn, (void*)&arr };
  hipLaunchCooperativeKernel((void*)k_main, dim3(NWG), dim3(512), args,
                             (unsigned int)SMEM_BYTES, stream);
}

// Round 15
// 1640.836 us; speedup vs baseline: 1.8996x; 1.1541x over previous
//
#include <hip/hip_runtime.h>
#include <hip/hip_bf16.h>

typedef __hip_bfloat16 bf16;
typedef unsigned short u16;
typedef unsigned long long u64;
using frag  = __attribute__((ext_vector_type(8))) short;   // 8 bf16
using f32x4 = __attribute__((ext_vector_type(4))) float;   // 4 fp32 acc

static constexpr int T_  = 128;
static constexpr int B_  = 512;
static constexpr int H_  = 512;
static constexpr int K_  = 512;
static constexpr int G4_ = 2048;
static constexpr int NWG = 256;

// dynamic LDS: frag-blocked weights only (128 blocks x 1KB)
static constexpr size_t W_BYTES = 131072;
static constexpr size_t SMEM_BYTES = W_BYTES;

// coherent (agent-scope, L1/L2-bypassing) 16B load — cross-XCD layer0->layer1 only
__device__ __forceinline__ frag ld_coh(const u16* p) {
  u64 lo = __hip_atomic_load((const u64*)p,       __ATOMIC_RELAXED, __HIP_MEMORY_SCOPE_AGENT);
  u64 hi = __hip_atomic_load((const u64*)(p + 4), __ATOMIC_RELAXED, __HIP_MEMORY_SCOPE_AGENT);
  union { u64 q[2]; frag f; } u;
  u.q[0] = lo; u.q[1] = hi;
  return u.f;
}

// ---------------- setup kernels ----------------

__global__ void k_f32_to_bf16_v4(const float4* __restrict__ src,
                                 ushort4* __restrict__ dst, int n4) {
  int i = blockIdx.x * blockDim.x + threadIdx.x;
  int stride = gridDim.x * blockDim.x;
  for (; i < n4; i += stride) {
    float4 v = src[i];
    ushort4 o;
    bf16 t0 = __float2bfloat16(v.x); o.x = *reinterpret_cast<u16*>(&t0);
    bf16 t1 = __float2bfloat16(v.y); o.y = *reinterpret_cast<u16*>(&t1);
    bf16 t2 = __float2bfloat16(v.z); o.z = *reinterpret_cast<u16*>(&t2);
    bf16 t3 = __float2bfloat16(v.w); o.w = *reinterpret_cast<u16*>(&t3);
    dst[i] = o;
  }
}

__global__ void k_bias(const float* __restrict__ bih0, const float* __restrict__ bhh0,
                       const float* __restrict__ bih1, const float* __restrict__ bhh1,
                       float* __restrict__ bsum0, float* __restrict__ bsum1) {
  int i = blockIdx.x * blockDim.x + threadIdx.x;
  if (i < G4_) {
    bsum0[i] = bih0[i] + bhh0[i];
    bsum1[i] = bih1[i] + bhh1[i];
  }
}

// initial h into per-layer L2-local buffers: layer0 -> bufA0 par0, layer1 -> bufA1 par1
__global__ void k_init2(const float* __restrict__ h0,
                        u16* __restrict__ bufA0, u16* __restrict__ bufA1) {
  int i = blockIdx.x * blockDim.x + threadIdx.x;
  int n = B_ * H_;
  if (i < n) {
    bf16 a = __float2bfloat16(h0[i]);
    bf16 b = __float2bfloat16(h0[n + i]);
    bufA0[i] = *reinterpret_cast<u16*>(&a);          // parity 0
    bufA1[n + i] = *reinterpret_cast<u16*>(&b);      // parity 1
  }
}

__global__ void k_zero(int* p) {
  int i = blockIdx.x * blockDim.x + threadIdx.x;
  if (i < 256) p[i] = 0;
}

// ---------------- persistent LSTM kernel ----------------
// R12 base (best): 256 WGs x 512 thr, lb = wg&7 -> layer = lb>>2, bg = lb&3,
// cg = wg>>3; WG owns rows [bg*128,+128) x h-cols [cg*16,+16); wave w owns
// rows [bg*128 + w*16,+16), all 4 gates; frag-blocked weight LDS; h-self via
// plain L2 (bufA) + per-phase buffer_inv sc0; layer0 dual-stores h0 (plain ->
// bufA0, agent atomic -> h0buf/L3); layer1 x via ld_coh.
// NEW (R15): dependency-split barrier, x-part hoisted above the wait.
//   Phase p waits:
//     L0: (nothing) -> x-part -> wait {L0set>=p AND L1set>=p} -> inv -> h-part
//     L1: wait {L0set>=p} -> x-part -> wait {L1set>=p} -> inv -> h-part
//   Arrival: own-slot flag store (= p+1) after vmcnt(0)+syncthreads.
//   Flag slots: wg = cg*8 + layer*4 + bg. L0 set of domain bg: {c*8+bg},
//   L1 set: {c*8+4+bg}, c = 0..31. Wave 0 polls a set with 64 lanes (2/slot).
__global__ __launch_bounds__(512, 2)
void k_main(const u16* __restrict__ latb,
            const u16* __restrict__ W0i, const u16* __restrict__ W0h,
            const u16* __restrict__ W1i, const u16* __restrict__ W1h,
            const float* __restrict__ bs0, const float* __restrict__ bs1,
            const int* __restrict__ reset,   // (T,B)
            const float* __restrict__ c0,    // (2,B,H)
            u16* __restrict__ h0buf,         // [2][B][H] coherent cross-layer h0
            u16* __restrict__ bufA0,         // [2][B][H] layer0 h-self (L2-local)
            u16* __restrict__ bufA1,         // [2][B][H] layer1 h-self (L2-local)
            float* __restrict__ hidden,      // (T,B,H)
            float* __restrict__ hn,          // (2,B,H)
            float* __restrict__ cn,          // (2,B,H)
            int* __restrict__ arr) {         // 256 flag slots, one per WG
  extern __shared__ char smem_raw[];
  u16* wlds = (u16*)smem_raw;                // 128KB frag-blocked weights
  __shared__ float hstage[8][16][20];        // per-wave h packing tile

  const int tid   = threadIdx.x;
  const int wg    = blockIdx.x;
  const int lb    = wg & 7;
  const int layer = lb >> 2;
  const int bg    = lb & 3;
  const int cg    = wg >> 3;
  const int hbase = cg * 16;
  const int rowbase = bg * 128;
  const int wave  = tid >> 6;                  // 0..7
  const int lane  = tid & 63;
  const int r16   = lane & 15;
  const int kq    = lane >> 4;                 // 0..3
  const int wrow_local = wave * 16;            // wave's batch offset within WG
  const int wrow0 = rowbase + wrow_local;

  const u16* Wih = layer ? W1i : W0i;
  const u16* Whh = layer ? W1h : W0h;
  const float* bs = layer ? bs1 : bs0;
  u16* bufA_self = layer ? bufA1 : bufA0;

  // poll slot indices (wave 0 only uses these)
  const int slotPair = (lane >> 1) * 8 + (lane & 1) * 4 + bg;  // L0+L1 sets
  const int slotL0   = (lane & 31) * 8 + bg;                   // L0 set (2 lanes/slot)
  const int slotL1   = (lane & 31) * 8 + 4 + bg;               // L1 set

  // ---- stage weights into frag-blocked LDS (once) ----
  // chunk c = fb*64 + l ; fb = ni*32 + kslot ; kslot<16 -> W_ih, else W_hh
  for (int it = 0; it < 16; ++it) {
    int c = it * 512 + tid;                    // 0..8191
    int fb = c >> 6, l = c & 63;
    int ni = fb >> 5, kslot = fb & 31;
    int col = hbase + (l & 15);
    int klocal = (kslot & 15) * 32 + (l >> 4) * 8;
    const u16* M = (kslot < 16) ? Wih : Whh;
    const u16* src = M + (size_t)(ni * H_ + col) * K_ + klocal;
    *(float4*)(wlds + ((size_t)c) * 8) = *(const float4*)src;
  }

  // per-lane gate biases (col = hbase + r16)
  float bias[4];
  #pragma unroll
  for (int g = 0; g < 4; ++g) bias[g] = bs[g * H_ + hbase + r16];

  // c-state registers: j -> row = wrow0 + kq*4 + j, col = hbase + r16
  float creg[4];
  #pragma unroll
  for (int j = 0; j < 4; ++j)
    creg[j] = c0[((size_t)layer * B_ + (wrow0 + kq * 4 + j)) * H_ + hbase + r16];

  __syncthreads();

  for (int p = 0; p <= T_; ++p) {
    const int t = layer ? (p - 1) : p;
    const bool active = (t >= 0 && t < T_);
    float hnew_r[4], cnew_r[4];
    f32x4 acc[4] = {};
    const int* rst_t = reset + (size_t)t * B_;
    const int ra0 = active ? rst_t[wrow0 + r16] : 0;

    // ================= x-part (hoisted above the join) =================
    if (active) {
      if (layer == 0) {
        const u16* x0 = latb + (size_t)t * B_ * K_ + (size_t)(wrow0 + r16) * K_ + kq * 8;
        #pragma unroll
        for (int s = 0; s < 16; ++s) {
          frag a = *reinterpret_cast<const frag*>(x0 + s * 32);
          #pragma unroll
          for (int ni = 0; ni < 4; ++ni) {
            frag bx = *reinterpret_cast<const frag*>(
                wlds + ((size_t)((ni * 32 + s) * 64 + lane)) * 8);
            acc[ni] = __builtin_amdgcn_mfma_f32_16x16x32_bf16(a, bx, acc[ni], 0, 0, 0);
          }
        }
      } else {
        // wait for layer0 of this domain to have completed phase p-1 (x = h0buf[p&1])
        if (wave == 0) {
          while (__hip_atomic_load(arr + slotL0, __ATOMIC_RELAXED,
                                   __HIP_MEMORY_SCOPE_AGENT) < p)
            __builtin_amdgcn_s_sleep(2);
        }
        __syncthreads();
        const u16* x0 = h0buf + (size_t)(p & 1) * B_ * H_
                        + (size_t)(wrow0 + r16) * H_ + kq * 8;
        #pragma unroll
        for (int s = 0; s < 16; ++s) {
          frag a = ld_coh(x0 + s * 32);
          #pragma unroll
          for (int ni = 0; ni < 4; ++ni) {
            frag bx = *reinterpret_cast<const frag*>(
                wlds + ((size_t)((ni * 32 + s) * 64 + lane)) * 8);
            acc[ni] = __builtin_amdgcn_mfma_f32_16x16x32_bf16(a, bx, acc[ni], 0, 0, 0);
          }
        }
      }
    }

    // ================= join for h-part (+ store anti-deps) =================
    if (wave == 0) {
      if (layer == 0) {
        // needs L0set>=p (h-self) and L1set>=p (h0buf anti-dep)
        while (__hip_atomic_load(arr + slotPair, __ATOMIC_RELAXED,
                                 __HIP_MEMORY_SCOPE_AGENT) < p)
          __builtin_amdgcn_s_sleep(2);
      } else {
        // needs L1set>=p (h-self + bufA1 anti-dep)
        while (__hip_atomic_load(arr + slotL1, __ATOMIC_RELAXED,
                                 __HIP_MEMORY_SCOPE_AGENT) < p)
          __builtin_amdgcn_s_sleep(2);
      }
    }
    __syncthreads();
    // L1-only invalidate: h-self lines written by sibling CUs last phase.
    asm volatile("buffer_inv sc0" ::: "memory");

    // ================= h-part + elementwise + h stores =================
    if (active) {
      const u16* Hp = bufA_self + (size_t)(p & 1) * B_ * H_;
      u16* HnA      = bufA_self + (size_t)((p + 1) & 1) * B_ * H_;
      u16* Hn0c     = h0buf + (size_t)((p + 1) & 1) * B_ * H_;   // layer0 only

      const u16* hp0 = Hp + (size_t)(wrow0 + r16) * H_ + kq * 8;
      const frag zf = {};

      #pragma unroll
      for (int s = 0; s < 16; ++s) {
        frag ah = ra0 ? zf : *reinterpret_cast<const frag*>(hp0 + s * 32);
        #pragma unroll
        for (int ni = 0; ni < 4; ++ni) {
          frag bh = *reinterpret_cast<const frag*>(
              wlds + ((size_t)((ni * 32 + 16 + s) * 64 + lane)) * 8);
          acc[ni] = __builtin_amdgcn_mfma_f32_16x16x32_bf16(ah, bh, acc[ni], 0, 0, 0);
        }
      }

      // cell elementwise: lane-local (4 outputs: rows kq*4+j, col r16)
      #pragma unroll
      for (int j = 0; j < 4; ++j) {
        const int rstj = rst_t[wrow0 + kq * 4 + j];
        float gi = acc[0][j] + bias[0];
        float gf = acc[1][j] + bias[1];
        float gg = acc[2][j] + bias[2];
        float go = acc[3][j] + bias[3];
        float iv = 1.f / (1.f + __expf(-gi));
        float fv = 1.f / (1.f + __expf(-gf));
        float gv = 1.f - 2.f / (__expf(2.f * gg) + 1.f);   // tanh
        float ov = 1.f / (1.f + __expf(-go));
        float ce = rstj ? 0.f : creg[j];
        float cnew = fv * ce + iv * gv;
        float hnew = ov * (1.f - 2.f / (__expf(2.f * cnew) + 1.f));
        creg[j] = cnew;
        cnew_r[j] = cnew;
        hnew_r[j] = hnew;
        hstage[wave][kq * 4 + j][r16] = hnew;   // wave-local LDS (in-wave order)
      }

      // pack + h stores: lane -> (row = lane>>2, 4 cols at (lane&3)*4)
      {
        const int prow = lane >> 2;
        const int pc4  = lane & 3;
        float4 v = *reinterpret_cast<const float4*>(&hstage[wave][prow][pc4 * 4]);
        bf16 b0 = __float2bfloat16(v.x), b1 = __float2bfloat16(v.y);
        bf16 b2 = __float2bfloat16(v.z), b3 = __float2bfloat16(v.w);
        u64 pk = (u64)*reinterpret_cast<u16*>(&b0)
               | ((u64)*reinterpret_cast<u16*>(&b1) << 16)
               | ((u64)*reinterpret_cast<u16*>(&b2) << 32)
               | ((u64)*reinterpret_cast<u16*>(&b3) << 48);
        const size_t hoff = (size_t)(wrow0 + prow) * H_ + hbase + pc4 * 4;
        *(u64*)(HnA + hoff) = pk;                       // plain -> local L2
        if (layer == 0) {
          __hip_atomic_store((u64*)(Hn0c + hoff), pk,
                             __ATOMIC_RELAXED, __HIP_MEMORY_SCOPE_AGENT);  // -> L3
        }
      }
    }

    // ---- arrival: own-slot flag store (= p+1) after h stores acked ----
    if (p < T_) {
      asm volatile("s_waitcnt vmcnt(0)" ::: "memory");
      __syncthreads();
      if (tid == 0)
        __hip_atomic_store(arr + wg, p + 1, __ATOMIC_RELAXED, __HIP_MEMORY_SCOPE_AGENT);
    }

    // ---- deferred output stores (overlap with next phase's x-part) ----
    if (active) {
      float* hidden_t = hidden + (size_t)t * B_ * H_;
      #pragma unroll
      for (int j = 0; j < 4; ++j) {
        const size_t off = (size_t)(wrow0 + kq * 4 + j) * H_ + hbase + r16;
        if (layer) hidden_t[off] = hnew_r[j];
        if (t == T_ - 1) {
          hn[(size_t)layer * B_ * H_ + off] = hnew_r[j];
          cn[(size_t)layer * B_ * H_ + off] = cnew_r[j];
        }
      }
    }
  }
}

// ---------------- host ----------------

extern "C" void kernel_launch(void* const* d_in, const int* in_sizes, int n_in,
                              void* d_out, int out_size, void* d_ws, size_t ws_size,
                              hipStream_t stream) {
  (void)in_sizes; (void)n_in; (void)out_size; (void)ws_size;

  const float* latent = (const float*)d_in[0];
  const float* h0in   = (const float*)d_in[1];
  const float* c0in   = (const float*)d_in[2];
  const int*   reset  = (const int*)d_in[3];
  const float* W_ih0  = (const float*)d_in[4];
  const float* W_hh0  = (const float*)d_in[5];
  const float* b_ih0  = (const float*)d_in[6];
  const float* b_hh0  = (const float*)d_in[7];
  const float* W_ih1  = (const float*)d_in[8];
  const float* W_hh1  = (const float*)d_in[9];
  const float* b_ih1  = (const float*)d_in[10];
  const float* b_hh1  = (const float*)d_in[11];

  float* out    = (float*)d_out;
  float* hidden = out;                               // (T,B,H)
  float* hn     = out + (size_t)T_ * B_ * H_;        // (2,B,H)
  float* cn     = hn + (size_t)2 * B_ * H_;          // (2,B,H)

  // workspace layout
  char* ws = (char*)d_ws;
  u16* latb  = (u16*)ws;                             // T*B*K bf16 (64 MiB)
  u16* wih0b = latb + (size_t)T_ * B_ * K_;
  u16* whh0b = wih0b + (size_t)G4_ * K_;
  u16* wih1b = whh0b + (size_t)G4_ * K_;
  u16* whh1b = wih1b + (size_t)G4_ * K_;
  float* bsum0 = (float*)(whh1b + (size_t)G4_ * K_);
  float* bsum1 = bsum0 + G4_;
  u16* h0buf = (u16*)(bsum1 + G4_);                  // [2][B][H] coherent
  u16* bufA0 = h0buf + (size_t)2 * B_ * H_;          // [2][B][H] L2-local
  u16* bufA1 = bufA0 + (size_t)2 * B_ * H_;          // [2][B][H] L2-local
  int* arr   = (int*)(bufA1 + (size_t)2 * B_ * H_);  // 256 flag slots

  // conversions / init (stream-ordered)
  int n_lat4 = T_ * B_ * K_ / 4;
  k_f32_to_bf16_v4<<<2048, 256, 0, stream>>>((const float4*)latent, (ushort4*)latb, n_lat4);
  int n_w4 = G4_ * K_ / 4;
  k_f32_to_bf16_v4<<<256, 256, 0, stream>>>((const float4*)W_ih0, (ushort4*)wih0b, n_w4);
  k_f32_to_bf16_v4<<<256, 256, 0, stream>>>((const float4*)W_hh0, (ushort4*)whh0b, n_w4);
  k_f32_to_bf16_v4<<<256, 256, 0, stream>>>((const float4*)W_ih1, (ushort4*)wih1b, n_w4);
  k_f32_to_bf16_v4<<<256, 256, 0, stream>>>((const float4*)W_hh1, (ushort4*)whh1b, n_w4);
  k_bias<<<(G4_ + 255) / 256, 256, 0, stream>>>(b_ih0, b_hh0, b_ih1, b_hh1, bsum0, bsum1);
  k_init2<<<(B_ * H_ + 255) / 256, 256, 0, stream>>>(h0in, bufA0, bufA1);
  k_zero<<<1, 256, 0, stream>>>(arr);

  // persistent cooperative kernel
  hipFuncSetAttribute((const void*)k_main, hipFuncAttributeMaxDynamicSharedMemorySize,
                      (int)SMEM_BYTES);
  void* args[] = { (void*)&latb, (void*)&wih0b, (void*)&whh0b, (void*)&wih1b, (void*)&whh1b,
                   (void*)&bsum0, (void*)&bsum1, (void*)&reset, (void*)&c0in,
                   (void*)&h0buf, (void*)&bufA0, (void*)&bufA1,
                   (void*)&hidden, (void*)&hn, (void*)&cn, (void*)&arr };
  hipLaunchCooperativeKernel((void*)k_main, dim3(NWG), dim3(512), args,
                             (unsigned int)SMEM_BYTES, stream);
}

// Round 16
// 1385.203 us; speedup vs baseline: 2.2502x; 1.1845x over previous
//
#include <hip/hip_runtime.h>
#include <hip/hip_bf16.h>

typedef __hip_bfloat16 bf16;
typedef unsigned short u16;
typedef unsigned long long u64;
using frag  = __attribute__((ext_vector_type(8))) short;   // 8 bf16
using f32x4 = __attribute__((ext_vector_type(4))) float;   // 4 fp32 acc

static constexpr int T_  = 128;
static constexpr int B_  = 512;
static constexpr int H_  = 512;
static constexpr int K_  = 512;
static constexpr int G4_ = 2048;
static constexpr int NWG = 256;

// dynamic LDS: frag-blocked weights only (128 blocks x 1KB)
static constexpr size_t W_BYTES = 131072;
static constexpr size_t SMEM_BYTES = W_BYTES;

// ---------------- setup kernels ----------------

__global__ void k_f32_to_bf16_v4(const float4* __restrict__ src,
                                 ushort4* __restrict__ dst, int n4) {
  int i = blockIdx.x * blockDim.x + threadIdx.x;
  int stride = gridDim.x * blockDim.x;
  for (; i < n4; i += stride) {
    float4 v = src[i];
    ushort4 o;
    bf16 t0 = __float2bfloat16(v.x); o.x = *reinterpret_cast<u16*>(&t0);
    bf16 t1 = __float2bfloat16(v.y); o.y = *reinterpret_cast<u16*>(&t1);
    bf16 t2 = __float2bfloat16(v.z); o.z = *reinterpret_cast<u16*>(&t2);
    bf16 t3 = __float2bfloat16(v.w); o.w = *reinterpret_cast<u16*>(&t3);
    dst[i] = o;
  }
}

__global__ void k_bias(const float* __restrict__ bih0, const float* __restrict__ bhh0,
                       const float* __restrict__ bih1, const float* __restrict__ bhh1,
                       float* __restrict__ bsum0, float* __restrict__ bsum1) {
  int i = blockIdx.x * blockDim.x + threadIdx.x;
  if (i < G4_) {
    bsum0[i] = bih0[i] + bhh0[i];
    bsum1[i] = bih1[i] + bhh1[i];
  }
}

// initial h into per-layer L2-local buffers: layer0 -> bufA0 par0, layer1 -> bufA1 par1
__global__ void k_init2(const float* __restrict__ h0,
                        u16* __restrict__ bufA0, u16* __restrict__ bufA1) {
  int i = blockIdx.x * blockDim.x + threadIdx.x;
  int n = B_ * H_;
  if (i < n) {
    bf16 a = __float2bfloat16(h0[i]);
    bf16 b = __float2bfloat16(h0[n + i]);
    bufA0[i] = *reinterpret_cast<u16*>(&a);          // parity 0
    bufA1[n + i] = *reinterpret_cast<u16*>(&b);      // parity 1
  }
}

__global__ void k_zero(int* p) {
  int i = blockIdx.x * blockDim.x + threadIdx.x;
  if (i < 256) p[i] = 0;
}

// ---------------- persistent LSTM kernel ----------------
// R12 base: 256 WGs x 512 thr, lb = wg&7 -> layer = lb>>2, bg = lb&3, cg = wg>>3;
// WG owns rows [bg*128,+128) x h-cols [cg*16,+16); wave w owns rows
// [bg*128 + w*16,+16), all 4 gates; frag-blocked weight LDS (conflict-free).
// h-self: bufA{layer}, plain L2 stores/loads + per-phase buffer_inv sc0 (L1-only).
// NEW (R16): cross-layer h0 via TIME-INDEXED h0seq[T][B][H] (64 MB, L3-resident).
//   Writer (layer0, phase p = t): agent-atomic u64 stores -> L3 (as before).
//   Reader (layer1, phase p, t = p-1): PLAIN CACHED loads — addresses are fresh
//   every phase, so reader L1/L2 are guaranteed cold -> fill from L3 (correct:
//   flag ordering guarantees stores landed), and the L2 fill is SHARED by all
//   32 column-WGs of the XCD (was: 32x duplicated L2-bypassing atomic reads).
// Sync: per-WG flag slot (no RMW); wave 0 polls 64 pair-domain slots in parallel.
// c-state in regs; hidden/hn/cn stores deferred past flag store.
__global__ __launch_bounds__(512, 2)
void k_main(const u16* __restrict__ latb,
            const u16* __restrict__ W0i, const u16* __restrict__ W0h,
            const u16* __restrict__ W1i, const u16* __restrict__ W1h,
            const float* __restrict__ bs0, const float* __restrict__ bs1,
            const int* __restrict__ reset,   // (T,B)
            const float* __restrict__ c0,    // (2,B,H)
            u16* __restrict__ h0seq,         // [T][B][H] layer0 output sequence
            u16* __restrict__ bufA0,         // [2][B][H] layer0 h-self (L2-local)
            u16* __restrict__ bufA1,         // [2][B][H] layer1 h-self (L2-local)
            float* __restrict__ hidden,      // (T,B,H)
            float* __restrict__ hn,          // (2,B,H)
            float* __restrict__ cn,          // (2,B,H)
            int* __restrict__ arr) {         // 256 flag slots, one per WG
  extern __shared__ char smem_raw[];
  u16* wlds = (u16*)smem_raw;                // 128KB frag-blocked weights
  __shared__ float hstage[8][16][20];        // per-wave h packing tile

  const int tid   = threadIdx.x;
  const int wg    = blockIdx.x;
  const int lb    = wg & 7;
  const int layer = lb >> 2;
  const int bg    = lb & 3;
  const int cg    = wg >> 3;
  const int hbase = cg * 16;
  const int rowbase = bg * 128;
  const int wave  = tid >> 6;                  // 0..7
  const int lane  = tid & 63;
  const int r16   = lane & 15;
  const int kq    = lane >> 4;                 // 0..3
  const int wrow_local = wave * 16;            // wave's batch offset within WG
  const int wrow0 = rowbase + wrow_local;

  const u16* Wih = layer ? W1i : W0i;
  const u16* Whh = layer ? W1h : W0h;
  const float* bs = layer ? bs1 : bs0;
  u16* bufA_self = layer ? bufA1 : bufA0;

  // ---- stage weights into frag-blocked LDS (once) ----
  // chunk c = fb*64 + l ; fb = ni*32 + kslot ; kslot<16 -> W_ih, else W_hh
  for (int it = 0; it < 16; ++it) {
    int c = it * 512 + tid;                    // 0..8191
    int fb = c >> 6, l = c & 63;
    int ni = fb >> 5, kslot = fb & 31;
    int col = hbase + (l & 15);
    int klocal = (kslot & 15) * 32 + (l >> 4) * 8;
    const u16* M = (kslot < 16) ? Wih : Whh;
    const u16* src = M + (size_t)(ni * H_ + col) * K_ + klocal;
    *(float4*)(wlds + ((size_t)c) * 8) = *(const float4*)src;
  }

  // per-lane gate biases (col = hbase + r16)
  float bias[4];
  #pragma unroll
  for (int g = 0; g < 4; ++g) bias[g] = bs[g * H_ + hbase + r16];

  // c-state registers: j -> row = wrow0 + kq*4 + j, col = hbase + r16
  float creg[4];
  #pragma unroll
  for (int j = 0; j < 4; ++j)
    creg[j] = c0[((size_t)layer * B_ + (wrow0 + kq * 4 + j)) * H_ + hbase + r16];

  __syncthreads();

  for (int p = 0; p <= T_; ++p) {
    // L1-only invalidate: h-self (bufA) lines written by sibling CUs last phase
    // must not be served from stale L1. L2 (same XCD) is current.
    if (p) { asm volatile("buffer_inv sc0" ::: "memory"); }

    const int t = layer ? (p - 1) : p;
    const bool active = (t >= 0 && t < T_);
    float hnew_r[4], cnew_r[4];

    if (active) {
      // x source: layer0 = latent[t] (bf16); layer1 = h0seq[t] (plain cached,
      // cold-by-construction in this XCD's L1/L2 -> shared L3 fill)
      const u16* X  = layer ? (h0seq + (size_t)t * B_ * H_)
                            : (latb + (size_t)t * B_ * K_);
      const u16* Hp = bufA_self + (size_t)(p & 1) * B_ * H_;
      u16* HnA      = bufA_self + (size_t)((p + 1) & 1) * B_ * H_;

      const int* rst_t = reset + (size_t)t * B_;
      const int ra0 = rst_t[wrow0 + r16];           // mask for this lane's A row
      const u16* x0  = X  + (size_t)(wrow0 + r16) * K_ + kq * 8;
      const u16* hp0 = Hp + (size_t)(wrow0 + r16) * H_ + kq * 8;

      f32x4 acc[4] = {};
      const frag zf = {};

      // merged x+h K-loop: all plain loads, compiler-scheduled, frag-blocked B
      #pragma unroll
      for (int s = 0; s < 16; ++s) {
        frag a  = *reinterpret_cast<const frag*>(x0 + s * 32);
        frag ah = ra0 ? zf : *reinterpret_cast<const frag*>(hp0 + s * 32);
        #pragma unroll
        for (int ni = 0; ni < 4; ++ni) {
          frag bx = *reinterpret_cast<const frag*>(
              wlds + ((size_t)((ni * 32 + s) * 64 + lane)) * 8);
          frag bh = *reinterpret_cast<const frag*>(
              wlds + ((size_t)((ni * 32 + 16 + s) * 64 + lane)) * 8);
          acc[ni] = __builtin_amdgcn_mfma_f32_16x16x32_bf16(a,  bx, acc[ni], 0, 0, 0);
          acc[ni] = __builtin_amdgcn_mfma_f32_16x16x32_bf16(ah, bh, acc[ni], 0, 0, 0);
        }
      }

      // cell elementwise: lane-local (4 outputs: rows kq*4+j, col r16)
      #pragma unroll
      for (int j = 0; j < 4; ++j) {
        const int rstj = rst_t[wrow0 + kq * 4 + j];
        float gi = acc[0][j] + bias[0];
        float gf = acc[1][j] + bias[1];
        float gg = acc[2][j] + bias[2];
        float go = acc[3][j] + bias[3];
        float iv = 1.f / (1.f + __expf(-gi));
        float fv = 1.f / (1.f + __expf(-gf));
        float gv = 1.f - 2.f / (__expf(2.f * gg) + 1.f);   // tanh
        float ov = 1.f / (1.f + __expf(-go));
        float ce = rstj ? 0.f : creg[j];
        float cnew = fv * ce + iv * gv;
        float hnew = ov * (1.f - 2.f / (__expf(2.f * cnew) + 1.f));
        creg[j] = cnew;
        cnew_r[j] = cnew;
        hnew_r[j] = hnew;
        hstage[wave][kq * 4 + j][r16] = hnew;   // wave-local LDS (in-wave order)
      }

      // pack + h stores: lane -> (row = lane>>2, 4 cols at (lane&3)*4)
      {
        const int prow = lane >> 2;
        const int pc4  = lane & 3;
        float4 v = *reinterpret_cast<const float4*>(&hstage[wave][prow][pc4 * 4]);
        bf16 b0 = __float2bfloat16(v.x), b1 = __float2bfloat16(v.y);
        bf16 b2 = __float2bfloat16(v.z), b3 = __float2bfloat16(v.w);
        u64 pk = (u64)*reinterpret_cast<u16*>(&b0)
               | ((u64)*reinterpret_cast<u16*>(&b1) << 16)
               | ((u64)*reinterpret_cast<u16*>(&b2) << 32)
               | ((u64)*reinterpret_cast<u16*>(&b3) << 48);
        const size_t hoff = (size_t)(wrow0 + prow) * H_ + hbase + pc4 * 4;
        *(u64*)(HnA + hoff) = pk;                       // plain -> local L2
        if (layer == 0) {
          // timestep-indexed coherent store -> L3 (consumed by layer1 at p+1)
          __hip_atomic_store((u64*)(h0seq + (size_t)t * B_ * H_ + hoff), pk,
                             __ATOMIC_RELAXED, __HIP_MEMORY_SCOPE_AGENT);
        }
      }
    }

    // barrier arrival: own-slot flag store (no RMW), after h stores acked
    if (p < T_) {
      asm volatile("s_waitcnt vmcnt(0)" ::: "memory");
      __syncthreads();
      if (tid == 0)
        __hip_atomic_store(arr + wg, p + 1, __ATOMIC_RELAXED, __HIP_MEMORY_SCOPE_AGENT);
    }

    // deferred output stores (overlap with poll; nobody reads these in-kernel)
    if (active) {
      float* hidden_t = hidden + (size_t)t * B_ * H_;
      #pragma unroll
      for (int j = 0; j < 4; ++j) {
        const size_t off = (size_t)(wrow0 + kq * 4 + j) * H_ + hbase + r16;
        if (layer) hidden_t[off] = hnew_r[j];
        if (t == T_ - 1) {
          hn[(size_t)layer * B_ * H_ + off] = hnew_r[j];
          cn[(size_t)layer * B_ * H_ + off] = cnew_r[j];
        }
      }
    }

    // barrier wait: wave 0's 64 lanes poll the 64 pair-domain slots in parallel
    if (p < T_) {
      if (wave == 0) {
        const int slot = (lane >> 1) * 8 + (lane & 1) * 4 + bg;  // all 64 domain WGs
        while (__hip_atomic_load(arr + slot, __ATOMIC_RELAXED,
                                 __HIP_MEMORY_SCOPE_AGENT) < p + 1)
          __builtin_amdgcn_s_sleep(2);
      }
      __syncthreads();
    }
  }
}

// ---------------- host ----------------

extern "C" void kernel_launch(void* const* d_in, const int* in_sizes, int n_in,
                              void* d_out, int out_size, void* d_ws, size_t ws_size,
                              hipStream_t stream) {
  (void)in_sizes; (void)n_in; (void)out_size; (void)ws_size;

  const float* latent = (const float*)d_in[0];
  const float* h0in   = (const float*)d_in[1];
  const float* c0in   = (const float*)d_in[2];
  const int*   reset  = (const int*)d_in[3];
  const float* W_ih0  = (const float*)d_in[4];
  const float* W_hh0  = (const float*)d_in[5];
  const float* b_ih0  = (const float*)d_in[6];
  const float* b_hh0  = (const float*)d_in[7];
  const float* W_ih1  = (const float*)d_in[8];
  const float* W_hh1  = (const float*)d_in[9];
  const float* b_ih1  = (const float*)d_in[10];
  const float* b_hh1  = (const float*)d_in[11];

  float* out    = (float*)d_out;
  float* hidden = out;                               // (T,B,H)
  float* hn     = out + (size_t)T_ * B_ * H_;        // (2,B,H)
  float* cn     = hn + (size_t)2 * B_ * H_;          // (2,B,H)

  // workspace layout (~138 MB)
  char* ws = (char*)d_ws;
  u16* latb  = (u16*)ws;                             // T*B*K bf16 (64 MiB)
  u16* wih0b = latb + (size_t)T_ * B_ * K_;
  u16* whh0b = wih0b + (size_t)G4_ * K_;
  u16* wih1b = whh0b + (size_t)G4_ * K_;
  u16* whh1b = wih1b + (size_t)G4_ * K_;
  float* bsum0 = (float*)(whh1b + (size_t)G4_ * K_);
  float* bsum1 = bsum0 + G4_;
  u16* h0seq = (u16*)(bsum1 + G4_);                  // [T][B][H] (64 MiB)
  u16* bufA0 = h0seq + (size_t)T_ * B_ * H_;         // [2][B][H] L2-local
  u16* bufA1 = bufA0 + (size_t)2 * B_ * H_;          // [2][B][H] L2-local
  int* arr   = (int*)(bufA1 + (size_t)2 * B_ * H_);  // 256 flag slots

  // conversions / init (stream-ordered)
  int n_lat4 = T_ * B_ * K_ / 4;
  k_f32_to_bf16_v4<<<2048, 256, 0, stream>>>((const float4*)latent, (ushort4*)latb, n_lat4);
  int n_w4 = G4_ * K_ / 4;
  k_f32_to_bf16_v4<<<256, 256, 0, stream>>>((const float4*)W_ih0, (ushort4*)wih0b, n_w4);
  k_f32_to_bf16_v4<<<256, 256, 0, stream>>>((const float4*)W_hh0, (ushort4*)whh0b, n_w4);
  k_f32_to_bf16_v4<<<256, 256, 0, stream>>>((const float4*)W_ih1, (ushort4*)wih1b, n_w4);
  k_f32_to_bf16_v4<<<256, 256, 0, stream>>>((const float4*)W_hh1, (ushort4*)whh1b, n_w4);
  k_bias<<<(G4_ + 255) / 256, 256, 0, stream>>>(b_ih0, b_hh0, b_ih1, b_hh1, bsum0, bsum1);
  k_init2<<<(B_ * H_ + 255) / 256, 256, 0, stream>>>(h0in, bufA0, bufA1);
  k_zero<<<1, 256, 0, stream>>>(arr);

  // persistent cooperative kernel
  hipFuncSetAttribute((const void*)k_main, hipFuncAttributeMaxDynamicSharedMemorySize,
                      (int)SMEM_BYTES);
  void* args[] = { (void*)&latb, (void*)&wih0b, (void*)&whh0b, (void*)&wih1b, (void*)&whh1b,
                   (void*)&bsum0, (void*)&bsum1, (void*)&reset, (void*)&c0in,
                   (void*)&h0seq, (void*)&bufA0, (void*)&bufA1,
                   (void*)&hidden, (void*)&hn, (void*)&cn, (void*)&arr };
  hipLaunchCooperativeKernel((void*)k_main, dim3(NWG), dim3(512), args,
                             (unsigned int)SMEM_BYTES, stream);
}

// Round 17
// 1360.760 us; speedup vs baseline: 2.2906x; 1.0180x over previous
//
#include <hip/hip_runtime.h>
#include <hip/hip_bf16.h>

typedef __hip_bfloat16 bf16;
typedef unsigned short u16;
typedef unsigned long long u64;
using frag  = __attribute__((ext_vector_type(8))) short;   // 8 bf16
using f32x4 = __attribute__((ext_vector_type(4))) float;   // 4 fp32 acc

static constexpr int T_  = 128;
static constexpr int B_  = 512;
static constexpr int H_  = 512;
static constexpr int K_  = 512;
static constexpr int G4_ = 2048;
static constexpr int NWG = 256;

// dynamic LDS: frag-blocked weights only (128 blocks x 1KB)
static constexpr size_t W_BYTES = 131072;
static constexpr size_t SMEM_BYTES = W_BYTES;

// ---------------- setup kernels ----------------

__global__ void k_f32_to_bf16_v4(const float4* __restrict__ src,
                                 ushort4* __restrict__ dst, int n4) {
  int i = blockIdx.x * blockDim.x + threadIdx.x;
  int stride = gridDim.x * blockDim.x;
  for (; i < n4; i += stride) {
    float4 v = src[i];
    ushort4 o;
    bf16 t0 = __float2bfloat16(v.x); o.x = *reinterpret_cast<u16*>(&t0);
    bf16 t1 = __float2bfloat16(v.y); o.y = *reinterpret_cast<u16*>(&t1);
    bf16 t2 = __float2bfloat16(v.z); o.z = *reinterpret_cast<u16*>(&t2);
    bf16 t3 = __float2bfloat16(v.w); o.w = *reinterpret_cast<u16*>(&t3);
    dst[i] = o;
  }
}

__global__ void k_bias(const float* __restrict__ bih0, const float* __restrict__ bhh0,
                       const float* __restrict__ bih1, const float* __restrict__ bhh1,
                       float* __restrict__ bsum0, float* __restrict__ bsum1) {
  int i = blockIdx.x * blockDim.x + threadIdx.x;
  if (i < G4_) {
    bsum0[i] = bih0[i] + bhh0[i];
    bsum1[i] = bih1[i] + bhh1[i];
  }
}

// initial h into per-layer L2-local buffers: layer0 -> bufA0 par0, layer1 -> bufA1 par1
__global__ void k_init2(const float* __restrict__ h0,
                        u16* __restrict__ bufA0, u16* __restrict__ bufA1) {
  int i = blockIdx.x * blockDim.x + threadIdx.x;
  int n = B_ * H_;
  if (i < n) {
    bf16 a = __float2bfloat16(h0[i]);
    bf16 b = __float2bfloat16(h0[n + i]);
    bufA0[i] = *reinterpret_cast<u16*>(&a);          // parity 0
    bufA1[n + i] = *reinterpret_cast<u16*>(&b);      // parity 1
  }
}

__global__ void k_zero(int* p) {
  int i = blockIdx.x * blockDim.x + threadIdx.x;
  if (i < 256) p[i] = 0;
}

// ---------------- persistent LSTM kernel ----------------
// R16 base: 256 WGs x 512 thr, lb = wg&7 -> layer = lb>>2, bg = lb&3, cg = wg>>3;
// WG owns rows [bg*128,+128) x h-cols [cg*16,+16); wave w owns rows
// [bg*128 + w*16,+16), all 4 gates; frag-blocked weight LDS (conflict-free).
// h-self: bufA{layer}, plain L2 stores/loads + per-phase buffer_inv sc0 (L1-only).
// Cross-layer h0: TIME-INDEXED h0seq[T][B][H] — L0 agent-atomic stores -> L3;
// L1 plain cached loads (cold lines by construction -> shared L2 fill).
// NEW (R17): ASYMMETRIC BARRIER. h0seq is append-only, so L0 has NO dependency
// on L1: L0 polls only its own 32 flag slots (bufA0 parity WAR is covered by
// own-layer flags); L1 polls the 64-slot pair (needs L0's h0seq writes + its
// own bufA1 parity). L0 free-runs ahead; skew no longer couples the layers.
// c-state in regs; hidden/hn/cn stores deferred past flag store.
__global__ __launch_bounds__(512, 2)
void k_main(const u16* __restrict__ latb,
            const u16* __restrict__ W0i, const u16* __restrict__ W0h,
            const u16* __restrict__ W1i, const u16* __restrict__ W1h,
            const float* __restrict__ bs0, const float* __restrict__ bs1,
            const int* __restrict__ reset,   // (T,B)
            const float* __restrict__ c0,    // (2,B,H)
            u16* __restrict__ h0seq,         // [T][B][H] layer0 output sequence
            u16* __restrict__ bufA0,         // [2][B][H] layer0 h-self (L2-local)
            u16* __restrict__ bufA1,         // [2][B][H] layer1 h-self (L2-local)
            float* __restrict__ hidden,      // (T,B,H)
            float* __restrict__ hn,          // (2,B,H)
            float* __restrict__ cn,          // (2,B,H)
            int* __restrict__ arr) {         // 256 flag slots, one per WG
  extern __shared__ char smem_raw[];
  u16* wlds = (u16*)smem_raw;                // 128KB frag-blocked weights
  __shared__ float hstage[8][16][20];        // per-wave h packing tile

  const int tid   = threadIdx.x;
  const int wg    = blockIdx.x;
  const int lb    = wg & 7;
  const int layer = lb >> 2;
  const int bg    = lb & 3;
  const int cg    = wg >> 3;
  const int hbase = cg * 16;
  const int rowbase = bg * 128;
  const int wave  = tid >> 6;                  // 0..7
  const int lane  = tid & 63;
  const int r16   = lane & 15;
  const int kq    = lane >> 4;                 // 0..3
  const int wrow_local = wave * 16;            // wave's batch offset within WG
  const int wrow0 = rowbase + wrow_local;

  const u16* Wih = layer ? W1i : W0i;
  const u16* Whh = layer ? W1h : W0h;
  const float* bs = layer ? bs1 : bs0;
  u16* bufA_self = layer ? bufA1 : bufA0;

  // poll slots (wave 0 only): L0 -> own set (32 slots, 2 lanes each);
  // L1 -> pair set (64 slots, 1 lane each)
  const int slotOwn  = (lane & 31) * 8 + bg;                   // L0 set
  const int slotPair = (lane >> 1) * 8 + (lane & 1) * 4 + bg;  // L0+L1 sets

  // ---- stage weights into frag-blocked LDS (once) ----
  // chunk c = fb*64 + l ; fb = ni*32 + kslot ; kslot<16 -> W_ih, else W_hh
  for (int it = 0; it < 16; ++it) {
    int c = it * 512 + tid;                    // 0..8191
    int fb = c >> 6, l = c & 63;
    int ni = fb >> 5, kslot = fb & 31;
    int col = hbase + (l & 15);
    int klocal = (kslot & 15) * 32 + (l >> 4) * 8;
    const u16* M = (kslot < 16) ? Wih : Whh;
    const u16* src = M + (size_t)(ni * H_ + col) * K_ + klocal;
    *(float4*)(wlds + ((size_t)c) * 8) = *(const float4*)src;
  }

  // per-lane gate biases (col = hbase + r16)
  float bias[4];
  #pragma unroll
  for (int g = 0; g < 4; ++g) bias[g] = bs[g * H_ + hbase + r16];

  // c-state registers: j -> row = wrow0 + kq*4 + j, col = hbase + r16
  float creg[4];
  #pragma unroll
  for (int j = 0; j < 4; ++j)
    creg[j] = c0[((size_t)layer * B_ + (wrow0 + kq * 4 + j)) * H_ + hbase + r16];

  __syncthreads();

  for (int p = 0; p <= T_; ++p) {
    // L1-only invalidate: h-self (bufA) lines written by sibling CUs last phase
    // must not be served from stale L1. L2 (same XCD) is current.
    if (p) { asm volatile("buffer_inv sc0" ::: "memory"); }

    const int t = layer ? (p - 1) : p;
    const bool active = (t >= 0 && t < T_);
    float hnew_r[4], cnew_r[4];

    if (active) {
      // x source: layer0 = latent[t] (bf16); layer1 = h0seq[t] (plain cached,
      // cold-by-construction in this XCD's L1/L2 -> shared L3 fill)
      const u16* X  = layer ? (h0seq + (size_t)t * B_ * H_)
                            : (latb + (size_t)t * B_ * K_);
      const u16* Hp = bufA_self + (size_t)(p & 1) * B_ * H_;
      u16* HnA      = bufA_self + (size_t)((p + 1) & 1) * B_ * H_;

      const int* rst_t = reset + (size_t)t * B_;
      const int ra0 = rst_t[wrow0 + r16];           // mask for this lane's A row
      const u16* x0  = X  + (size_t)(wrow0 + r16) * K_ + kq * 8;
      const u16* hp0 = Hp + (size_t)(wrow0 + r16) * H_ + kq * 8;

      f32x4 acc[4] = {};
      const frag zf = {};

      // merged x+h K-loop: all plain loads, compiler-scheduled, frag-blocked B
      #pragma unroll
      for (int s = 0; s < 16; ++s) {
        frag a  = *reinterpret_cast<const frag*>(x0 + s * 32);
        frag ah = ra0 ? zf : *reinterpret_cast<const frag*>(hp0 + s * 32);
        #pragma unroll
        for (int ni = 0; ni < 4; ++ni) {
          frag bx = *reinterpret_cast<const frag*>(
              wlds + ((size_t)((ni * 32 + s) * 64 + lane)) * 8);
          frag bh = *reinterpret_cast<const frag*>(
              wlds + ((size_t)((ni * 32 + 16 + s) * 64 + lane)) * 8);
          acc[ni] = __builtin_amdgcn_mfma_f32_16x16x32_bf16(a,  bx, acc[ni], 0, 0, 0);
          acc[ni] = __builtin_amdgcn_mfma_f32_16x16x32_bf16(ah, bh, acc[ni], 0, 0, 0);
        }
      }

      // cell elementwise: lane-local (4 outputs: rows kq*4+j, col r16)
      #pragma unroll
      for (int j = 0; j < 4; ++j) {
        const int rstj = rst_t[wrow0 + kq * 4 + j];
        float gi = acc[0][j] + bias[0];
        float gf = acc[1][j] + bias[1];
        float gg = acc[2][j] + bias[2];
        float go = acc[3][j] + bias[3];
        float iv = 1.f / (1.f + __expf(-gi));
        float fv = 1.f / (1.f + __expf(-gf));
        float gv = 1.f - 2.f / (__expf(2.f * gg) + 1.f);   // tanh
        float ov = 1.f / (1.f + __expf(-go));
        float ce = rstj ? 0.f : creg[j];
        float cnew = fv * ce + iv * gv;
        float hnew = ov * (1.f - 2.f / (__expf(2.f * cnew) + 1.f));
        creg[j] = cnew;
        cnew_r[j] = cnew;
        hnew_r[j] = hnew;
        hstage[wave][kq * 4 + j][r16] = hnew;   // wave-local LDS (in-wave order)
      }

      // pack + h stores: lane -> (row = lane>>2, 4 cols at (lane&3)*4)
      {
        const int prow = lane >> 2;
        const int pc4  = lane & 3;
        float4 v = *reinterpret_cast<const float4*>(&hstage[wave][prow][pc4 * 4]);
        bf16 b0 = __float2bfloat16(v.x), b1 = __float2bfloat16(v.y);
        bf16 b2 = __float2bfloat16(v.z), b3 = __float2bfloat16(v.w);
        u64 pk = (u64)*reinterpret_cast<u16*>(&b0)
               | ((u64)*reinterpret_cast<u16*>(&b1) << 16)
               | ((u64)*reinterpret_cast<u16*>(&b2) << 32)
               | ((u64)*reinterpret_cast<u16*>(&b3) << 48);
        const size_t hoff = (size_t)(wrow0 + prow) * H_ + hbase + pc4 * 4;
        *(u64*)(HnA + hoff) = pk;                       // plain -> local L2
        if (layer == 0) {
          // timestep-indexed coherent store -> L3 (consumed by layer1 at p+1)
          __hip_atomic_store((u64*)(h0seq + (size_t)t * B_ * H_ + hoff), pk,
                             __ATOMIC_RELAXED, __HIP_MEMORY_SCOPE_AGENT);
        }
      }
    }

    // barrier arrival: own-slot flag store (no RMW), after h stores acked
    if (p < T_) {
      asm volatile("s_waitcnt vmcnt(0)" ::: "memory");
      __syncthreads();
      if (tid == 0)
        __hip_atomic_store(arr + wg, p + 1, __ATOMIC_RELAXED, __HIP_MEMORY_SCOPE_AGENT);
    }

    // deferred output stores (overlap with poll; nobody reads these in-kernel)
    if (active) {
      float* hidden_t = hidden + (size_t)t * B_ * H_;
      #pragma unroll
      for (int j = 0; j < 4; ++j) {
        const size_t off = (size_t)(wrow0 + kq * 4 + j) * H_ + hbase + r16;
        if (layer) hidden_t[off] = hnew_r[j];
        if (t == T_ - 1) {
          hn[(size_t)layer * B_ * H_ + off] = hnew_r[j];
          cn[(size_t)layer * B_ * H_ + off] = cnew_r[j];
        }
      }
    }

    // barrier wait — ASYMMETRIC:
    //   L0: own 32 slots only (h0seq append-only kills the cross-layer anti-dep)
    //   L1: 64-slot pair (needs L0's h0seq[t=p] written + own bufA1 parity)
    if (p < T_) {
      if (wave == 0) {
        if (layer == 0) {
          while (__hip_atomic_load(arr + slotOwn, __ATOMIC_RELAXED,
                                   __HIP_MEMORY_SCOPE_AGENT) < p + 1)
            __builtin_amdgcn_s_sleep(2);
        } else {
          while (__hip_atomic_load(arr + slotPair, __ATOMIC_RELAXED,
                                   __HIP_MEMORY_SCOPE_AGENT) < p + 1)
            __builtin_amdgcn_s_sleep(2);
        }
      }
      __syncthreads();
    }
  }
}

// ---------------- host ----------------

extern "C" void kernel_launch(void* const* d_in, const int* in_sizes, int n_in,
                              void* d_out, int out_size, void* d_ws, size_t ws_size,
                              hipStream_t stream) {
  (void)in_sizes; (void)n_in; (void)out_size; (void)ws_size;

  const float* latent = (const float*)d_in[0];
  const float* h0in   = (const float*)d_in[1];
  const float* c0in   = (const float*)d_in[2];
  const int*   reset  = (const int*)d_in[3];
  const float* W_ih0  = (const float*)d_in[4];
  const float* W_hh0  = (const float*)d_in[5];
  const float* b_ih0  = (const float*)d_in[6];
  const float* b_hh0  = (const float*)d_in[7];
  const float* W_ih1  = (const float*)d_in[8];
  const float* W_hh1  = (const float*)d_in[9];
  const float* b_ih1  = (const float*)d_in[10];
  const float* b_hh1  = (const float*)d_in[11];

  float* out    = (float*)d_out;
  float* hidden = out;                               // (T,B,H)
  float* hn     = out + (size_t)T_ * B_ * H_;        // (2,B,H)
  float* cn     = hn + (size_t)2 * B_ * H_;          // (2,B,H)

  // workspace layout (~138 MB)
  char* ws = (char*)d_ws;
  u16* latb  = (u16*)ws;                             // T*B*K bf16 (64 MiB)
  u16* wih0b = latb + (size_t)T_ * B_ * K_;
  u16* whh0b = wih0b + (size_t)G4_ * K_;
  u16* wih1b = whh0b + (size_t)G4_ * K_;
  u16* whh1b = wih1b + (size_t)G4_ * K_;
  float* bsum0 = (float*)(whh1b + (size_t)G4_ * K_);
  float* bsum1 = bsum0 + G4_;
  u16* h0seq = (u16*)(bsum1 + G4_);                  // [T][B][H] (64 MiB)
  u16* bufA0 = h0seq + (size_t)T_ * B_ * H_;         // [2][B][H] L2-local
  u16* bufA1 = bufA0 + (size_t)2 * B_ * H_;          // [2][B][H] L2-local
  int* arr   = (int*)(bufA1 + (size_t)2 * B_ * H_);  // 256 flag slots

  // conversions / init (stream-ordered)
  int n_lat4 = T_ * B_ * K_ / 4;
  k_f32_to_bf16_v4<<<2048, 256, 0, stream>>>((const float4*)latent, (ushort4*)latb, n_lat4);
  int n_w4 = G4_ * K_ / 4;
  k_f32_to_bf16_v4<<<256, 256, 0, stream>>>((const float4*)W_ih0, (ushort4*)wih0b, n_w4);
  k_f32_to_bf16_v4<<<256, 256, 0, stream>>>((const float4*)W_hh0, (ushort4*)whh0b, n_w4);
  k_f32_to_bf16_v4<<<256, 256, 0, stream>>>((const float4*)W_ih1, (ushort4*)wih1b, n_w4);
  k_f32_to_bf16_v4<<<256, 256, 0, stream>>>((const float4*)W_hh1, (ushort4*)whh1b, n_w4);
  k_bias<<<(G4_ + 255) / 256, 256, 0, stream>>>(b_ih0, b_hh0, b_ih1, b_hh1, bsum0, bsum1);
  k_init2<<<(B_ * H_ + 255) / 256, 256, 0, stream>>>(h0in, bufA0, bufA1);
  k_zero<<<1, 256, 0, stream>>>(arr);

  // persistent cooperative kernel
  hipFuncSetAttribute((const void*)k_main, hipFuncAttributeMaxDynamicSharedMemorySize,
                      (int)SMEM_BYTES);
  void* args[] = { (void*)&latb, (void*)&wih0b, (void*)&whh0b, (void*)&wih1b, (void*)&whh1b,
                   (void*)&bsum0, (void*)&bsum1, (void*)&reset, (void*)&c0in,
                   (void*)&h0seq, (void*)&bufA0, (void*)&bufA1,
                   (void*)&hidden, (void*)&hn, (void*)&cn, (void*)&arr };
  hipLaunchCooperativeKernel((void*)k_main, dim3(NWG), dim3(512), args,
                             (unsigned int)SMEM_BYTES, stream);
}